// Round 3
// baseline (74.572 us; speedup 1.0000x reference)
//
#include <hip/hip_runtime.h>
#include <math.h>

// Problem constants
#define BATCH 32
#define HHWW  12544          // 112*112
#define CH    96
#define CH4   24             // CH/4
#define CR    24             // reduced channels
#define NBLK  28             // pooling blocks per batch
#define ROWS_PER_BLK (HHWW / NBLK)   // 448
#define RDIM  16             // row-threads per block

typedef float f32x4 __attribute__((ext_vector_type(4)));

// ---------------------------------------------------------------------------
// Kernel 1: per-block partial channel sums.
// grid = (BATCH, NBLK), block = (CH4, RDIM) = 384 threads.
// Wave reads 64 contiguous float4 = 1024B per issue (perfect coalescing).
// Normal (caching) loads keep the input L3-resident for kernel 2.
// ---------------------------------------------------------------------------
__global__ void se_pool_partial(const float* __restrict__ in,
                                float* __restrict__ partial) {
    const int b   = blockIdx.x;
    const int blk = blockIdx.y;
    const int q   = threadIdx.x;   // 0..23  channel quad
    const int r   = threadIdx.y;   // 0..15  row lane

    const f32x4* inb = (const f32x4*)(in) + (size_t)b * HHWW * CH4;

    f32x4 acc = (f32x4)(0.f);
    const int row0 = blk * ROWS_PER_BLK;
    #pragma unroll 4
    for (int row = row0 + r; row < row0 + ROWS_PER_BLK; row += RDIM) {
        acc += inb[(size_t)row * CH4 + q];
    }

    __shared__ f32x4 sdata[RDIM][CH4];
    sdata[r][q] = acc;
    __syncthreads();

    if (r == 0) {
        f32x4 s = sdata[0][q];
        #pragma unroll
        for (int k = 1; k < RDIM; ++k) s += sdata[k][q];
        ((f32x4*)partial)[((size_t)b * NBLK + blk) * CH4 + q] = s;
    }
}

// ---------------------------------------------------------------------------
// Kernel 2: fused gate-compute + scale.
// grid = (49, BATCH), block = 256. Each block:
//   (a) redundantly computes gate[96] for its batch from the 28 partials
//       (tiny: ~7k MACs, hides under startup / other waves' loads),
//   (b) scales 6144 consecutive float4 of that batch (24 per thread).
// Channel-quad of idx cycles with period 3 (256 % 24 == 16; 16*3 % 24 == 0),
// so each thread caches its 3 gate quads in registers -> inner loop is pure
// load/mul/NT-store.
// ---------------------------------------------------------------------------
__global__ void __launch_bounds__(256)
se_gate_scale(const f32x4* __restrict__ in,
              const float* __restrict__ partial,   // [BATCH][NBLK][CH]
              const float* __restrict__ w_reduce,  // [CH][CR]
              const float* __restrict__ b_reduce,  // [CR]
              const float* __restrict__ w_expand,  // [CR][CH]
              const float* __restrict__ b_expand,  // [CH]
              f32x4* __restrict__ out) {
    const int b = blockIdx.y;
    const int t = threadIdx.x;

    __shared__ float pooled[CH];
    __shared__ float hsw[CR];
    __shared__ float gateS[CH];

    if (t < CH) {
        float s = 0.f;
        #pragma unroll
        for (int k = 0; k < NBLK; ++k)
            s += partial[((size_t)b * NBLK + k) * CH + t];
        pooled[t] = s * (1.0f / (float)HHWW);
    }
    __syncthreads();

    if (t < CR) {
        float h = b_reduce[t];
        #pragma unroll
        for (int i = 0; i < CH; ++i)
            h += pooled[i] * w_reduce[i * CR + t];
        hsw[t] = h / (1.0f + expf(-h));   // swish
    }
    __syncthreads();

    if (t < CH) {
        float g = b_expand[t];
        #pragma unroll
        for (int j = 0; j < CR; ++j)
            g += hsw[j] * w_expand[j * CH + t];
        gateS[t] = 1.0f / (1.0f + expf(-g));
    }
    __syncthreads();

    // ---- scale phase ----
    const int q0 = t % CH4;
    const int q1 = (q0 + 16) % CH4;
    const int q2 = (q0 + 8) % CH4;
    const f32x4* g4 = (const f32x4*)gateS;
    const f32x4 g0 = g4[q0];
    const f32x4 g1 = g4[q1];
    const f32x4 g2 = g4[q2];

    const size_t boff = (size_t)b * (HHWW * CH4);
    int idx = blockIdx.x * 6144 + t;
    #pragma unroll
    for (int k = 0; k < 24; k += 3) {
        f32x4 v0 = in[boff + idx];
        f32x4 v1 = in[boff + idx + 256];
        f32x4 v2 = in[boff + idx + 512];
        __builtin_nontemporal_store(v0 * g0, &out[boff + idx]);
        __builtin_nontemporal_store(v1 * g1, &out[boff + idx + 256]);
        __builtin_nontemporal_store(v2 * g2, &out[boff + idx + 512]);
        idx += 768;
    }
}

extern "C" void kernel_launch(void* const* d_in, const int* in_sizes, int n_in,
                              void* d_out, int out_size, void* d_ws, size_t ws_size,
                              hipStream_t stream) {
    const float* in       = (const float*)d_in[0];
    const float* w_reduce = (const float*)d_in[1];
    const float* b_reduce = (const float*)d_in[2];
    const float* w_expand = (const float*)d_in[3];
    const float* b_expand = (const float*)d_in[4];
    float* out = (float*)d_out;

    // workspace: partials [BATCH][NBLK][CH] floats
    float* partial = (float*)d_ws;

    dim3 gridA(BATCH, NBLK);
    dim3 blockA(CH4, RDIM);
    se_pool_partial<<<gridA, blockA, 0, stream>>>(in, partial);

    dim3 gridB(49, BATCH);   // 49 * 6144 float4 = 301056 = HHWW*CH4 per batch
    se_gate_scale<<<gridB, 256, 0, stream>>>((const f32x4*)in, partial,
                                             w_reduce, b_reduce,
                                             w_expand, b_expand,
                                             (f32x4*)out);
}